// Round 8
// baseline (369.474 us; speedup 1.0000x reference)
//
#include <hip/hip_runtime.h>

typedef _Float16 half2_t __attribute__((ext_vector_type(2)));
typedef _Float16 f16x8 __attribute__((ext_vector_type(8)));
typedef float f32x4 __attribute__((ext_vector_type(4)));

#define DEC 256
#define TFULL 4096
#define WIN0 3584               // x window start (t0min-128 = 3712 >= 3584)
#define WLAYER_U32 11264        // preA 1024 + f 4096 + g 4096 + p 2048
#define WTOT_U32 (8 * WLAYER_U32)          // 90112
#define X16_U32 (32 * 512 * 16)            // 262144, x16t[b][tw512][cp16]
#define P_U32 (8 * 256 * 1024)             // skip partials, f16x2 packed
#define XP_U32 (WTOT_U32 + X16_U32)        // 352256
#define CTR_OFF (XP_U32 + P_U32)           // 256 counters
#define WS_NEEDF ((size_t)(CTR_OFF + 256) * 4)

#define HSTR 34                 // h LDS row stride (u32)
#define SSTR 36                 // s LDS row stride (u32), 16B-aligned rows
#define HU (64 * HSTR)          // 2176 u32
#define LDS_U32 (HU + 32 * SSTR)  // 3328 u32 = 13312 B

__device__ __forceinline__ float fast_tanh(float x) {
    float xa = fminf(fmaxf(x, -10.f), 10.f);
    float e = __expf(2.f * xa);
    return (e - 1.f) * __builtin_amdgcn_rcpf(e + 1.f);
}
__device__ __forceinline__ unsigned pk_rte(float a, float b) {
    union { _Float16 h[2]; unsigned u; } v;
    v.h[0] = (_Float16)a; v.h[1] = (_Float16)b; return v.u;
}
__device__ __forceinline__ half2_t h2(unsigned u) {
    return __builtin_bit_cast(half2_t, u);
}
__device__ __forceinline__ unsigned pkrtz(float a, float b) {
    return __builtin_bit_cast(unsigned, __builtin_amdgcn_cvt_pkrtz(a, b));
}

// ---------------- prep: pack weights + x window to f16; zero counters ----
// per-layer block (u32), all in the SAME MFMA A-frag convention
// (u32 e-th element of k-group kg for row o = k-pair (8kg+2e, 8kg+2e+1)):
//   [0,1024)      preA[kg4][o64][e4]   k=cin(32)
//   [1024,5120)   f16 [kb16][o64][e4]  k=2c+tap(128): u32 = (fw[o][4kb+e][0],[1])
//   [5120,9216)   g16 same
//   [9216,11264)  p16 [kg8][o64][e4]   k=c(64):  u32 = (pw[o][8kg+2e],[+1])
// then x16t[b32][tw512][cp16] at WTOT_U32 (transposed for B-frag uint4 loads).
// counters ctr[256] at CTR_OFF zeroed every call (no cross-call state).
__global__ __launch_bounds__(512) void wavenet_prep16(
    const float* __restrict__ x,
    const float* __restrict__ pre_w,
    const float* __restrict__ fw, const float* __restrict__ gw,
    const float* __restrict__ pw, unsigned* __restrict__ ws)
{
    int idx = blockIdx.x * 512 + threadIdx.x;
    if (idx >= XP_U32) {
        if (idx < XP_U32 + 256) ws[CTR_OFF + (idx - XP_U32)] = 0u;
        return;
    }
    unsigned v;
    if (idx < WTOT_U32) {
        int i = idx / WLAYER_U32;
        int r = idx - i * WLAYER_U32;
        if (r < 1024) {
            int kg = r >> 8, o = (r >> 2) & 63, e = r & 3;
            const float* p = pre_w + (i * 64 + o) * 32 + 8 * kg + 2 * e;
            v = pk_rte(p[0], p[1]);
        } else if (r < 5120) {
            int e2 = r - 1024;
            int kb = e2 >> 8, o = (e2 >> 2) & 63, e = e2 & 3;
            const float* p = fw + ((i * 64 + o) * 64 + 4 * kb + e) * 2;
            v = pk_rte(p[0], p[1]);
        } else if (r < 9216) {
            int e2 = r - 5120;
            int kb = e2 >> 8, o = (e2 >> 2) & 63, e = e2 & 3;
            const float* p = gw + ((i * 64 + o) * 64 + 4 * kb + e) * 2;
            v = pk_rte(p[0], p[1]);
        } else {
            int e3 = r - 9216;
            int kg = e3 >> 8, o = (e3 >> 2) & 63, e = e3 & 3;
            const float* p = pw + (i * 64 + o) * 64 + 8 * kg + 2 * e;
            v = pk_rte(p[0], p[1]);
        }
    } else {
        int e = idx - WTOT_U32;
        int b = e >> 13, r2 = e & 8191;
        int tw = r2 >> 4, cp = r2 & 15;
        const float* p = x + (size_t)(b * 32 + 2 * cp) * TFULL + WIN0 + tw;
        v = pk_rte(p[0], p[TFULL]);
    }
    ws[idx] = v;
}

// ---------------- layer-parallel all-MFMA kernel + fused head ----------------
// grid 2048 = layer(8) x bt(256); 512 threads; LDS 13316 B.
// Wave w: o-tile mt = w>>1; col-half nt = w&1.
// After P3, each block publishes its skip partial; the 8th arriver per bt
// (device-scope atomic) runs the dense head for that bt immediately.
__global__ __launch_bounds__(512) void wavenet_mfma2h(
    const unsigned* __restrict__ wsu,
    const float* __restrict__ pre_b,
    const float* __restrict__ filt_b, const float* __restrict__ gate_b,
    const float* __restrict__ post_b,
    unsigned* __restrict__ pout, unsigned* __restrict__ ctr,
    const float* __restrict__ d1_w, const float* __restrict__ d1_b,
    const float* __restrict__ d2_w, const float* __restrict__ d2_b,
    float* __restrict__ out)
{
    __shared__ __align__(16) unsigned lds[LDS_U32];
    __shared__ unsigned head_last;

    const int tid = threadIdx.x;
    const int i = blockIdx.x >> 8;
    const int bt = blockIdx.x & 255;
    const int b = bt >> 3;
    const int tile = bt & 7;
    const int dil = 1 << i;
    const int off1 = (dil < 32) ? dil : 32;
    const int t0 = TFULL - DEC + tile * 32;

    const int lane = tid & 63;
    const int wv = __builtin_amdgcn_readfirstlane(tid >> 6); // 0..7
    const int h4 = lane >> 4;       // 0..3 (k-group)
    const int ln = lane & 15;       // row/col within tile
    const int mt = wv >> 1;         // o-tile
    const int nt = wv & 1;          // col-half for P2/P3

    const unsigned* xw = wsu + WTOT_U32 + b * 8192;
    const unsigned* wl = wsu + i * WLAYER_U32;

    // ---- P1 (MFMA): h[o64][cw64] = relu(pre . x); store [cw][o] f16 ----
    {
        f16x8 a = *(const f16x8*)(wl + (h4 * 64 + mt * 16 + ln) * 4);
        float4 pb4 = *(const float4*)(pre_b + i * 64 + mt * 16 + 4 * h4);
#pragma unroll
        for (int ct2 = 0; ct2 < 2; ++ct2) {
            const int cw = (2 * nt + ct2) * 16 + ln;  // window col
            int ta = (dil >= 32) ? ((cw < 32) ? (t0 - dil + cw) : (t0 + cw - 32))
                                 : (t0 - dil + cw);
            const int tw = (ta - WIN0) & 511;   // wrap unused tail cols
            f16x8 bx = *(const f16x8*)(xw + tw * 16 + h4 * 4);
            f32x4 c = {0.f, 0.f, 0.f, 0.f};
            c = __builtin_amdgcn_mfma_f32_16x16x32_f16(a, bx, c, 0, 0, 0);
            // rows o = mt*16 + 4*h4 + reg, col cw
            uint2 hv;
            hv.x = pkrtz(fmaxf(c[0] + pb4.x, 0.f), fmaxf(c[1] + pb4.y, 0.f));
            hv.y = pkrtz(fmaxf(c[2] + pb4.z, 0.f), fmaxf(c[3] + pb4.w, 0.f));
            *(uint2*)&lds[cw * HSTR + mt * 8 + h4 * 2] = hv;
        }
    }
    __syncthreads();

    const int t = nt * 16 + ln;     // output col 0..31

    // ---- P2 (MFMA): F,G (K=128, k=2c+tap); s -> LDS [t][c] f16 ----
    {
        f32x4 cf = {0.f, 0.f, 0.f, 0.f};
        f32x4 cg = {0.f, 0.f, 0.f, 0.f};
        const unsigned* fA = wl + 1024;
        const unsigned* gA = wl + 5120;
#pragma unroll
        for (int ki = 0; ki < 4; ++ki) {
            const int kbg = 4 * ki + h4;     // c0 = 4*kbg
            const int c2 = 8 * ki + 2 * h4;  // c0/2
            uint2 lo = *(const uint2*)&lds[t * HSTR + c2];          // tap0
            uint2 hi = *(const uint2*)&lds[(t + off1) * HSTR + c2]; // tap1
            uint4 bf;
            bf.x = (lo.x & 0xffffu) | (hi.x << 16);
            bf.y = (lo.x >> 16) | (hi.x & 0xffff0000u);
            bf.z = (lo.y & 0xffffu) | (hi.y << 16);
            bf.w = (lo.y >> 16) | (hi.y & 0xffff0000u);
            f16x8 bfrag = __builtin_bit_cast(f16x8, bf);
            f16x8 af = *(const f16x8*)(fA + (kbg * 64 + mt * 16 + ln) * 4);
            f16x8 ag = *(const f16x8*)(gA + (kbg * 64 + mt * 16 + ln) * 4);
            cf = __builtin_amdgcn_mfma_f32_16x16x32_f16(af, bfrag, cf, 0, 0, 0);
            cg = __builtin_amdgcn_mfma_f32_16x16x32_f16(ag, bfrag, cg, 0, 0, 0);
        }
        float4 fb = *(const float4*)(filt_b + i * 64 + mt * 16 + 4 * h4);
        float4 gb = *(const float4*)(gate_b + i * 64 + mt * 16 + 4 * h4);
        float s0 = fast_tanh(cf[0] + fb.x) * fmaxf(cg[0] + gb.x, 0.f);
        float s1 = fast_tanh(cf[1] + fb.y) * fmaxf(cg[1] + gb.y, 0.f);
        float s2 = fast_tanh(cf[2] + fb.z) * fmaxf(cg[2] + gb.z, 0.f);
        float s3 = fast_tanh(cf[3] + fb.w) * fmaxf(cg[3] + gb.w, 0.f);
        uint2 sv;
        sv.x = pkrtz(s0, s1);
        sv.y = pkrtz(s2, s3);
        *(uint2*)&lds[HU + t * SSTR + mt * 8 + h4 * 2] = sv;
    }
    __syncthreads();

    // ---- P3 (MFMA): P (K=64, k=c); write packed skip partial ----
    {
        f32x4 cp = {0.f, 0.f, 0.f, 0.f};
        const unsigned* pA = wl + 9216;
#pragma unroll
        for (int ki = 0; ki < 2; ++ki) {
            const int kg = 4 * ki + h4;      // c0 = 8*kg
            f16x8 bs = *(const f16x8*)&lds[HU + t * SSTR + 4 * kg];
            f16x8 ap = *(const f16x8*)(pA + (kg * 64 + mt * 16 + ln) * 4);
            cp = __builtin_amdgcn_mfma_f32_16x16x32_f16(ap, bs, cp, 0, 0, 0);
        }
        float4 pb = *(const float4*)(post_b + i * 64 + mt * 16 + 4 * h4);
        float p0 = fmaxf(cp[0] + pb.x, 0.f);
        float p1 = fmaxf(cp[1] + pb.y, 0.f);
        float p2 = fmaxf(cp[2] + pb.z, 0.f);
        float p3 = fmaxf(cp[3] + pb.w, 0.f);
        const int op = mt * 8 + 2 * h4;      // packed o-pair index
        unsigned* po = pout + (size_t)(i * 256 + bt) * 1024;
        po[op * 32 + t] = pkrtz(p0, p1);
        po[(op + 1) * 32 + t] = pkrtz(p2, p3);
    }

    // ---- publish; 8th arriver for this bt runs the dense head ----
    __threadfence();   // make partial stores device-visible before the atomic
    if (tid == 0)
        head_last = (__hip_atomic_fetch_add(&ctr[bt], 1u, __ATOMIC_ACQ_REL,
                                            __HIP_MEMORY_SCOPE_AGENT) == 7u);
    __syncthreads();   // also: all waves done with P3's LDS reads
    if (!head_last) return;

    // ---- head: skip-sum (8 partials) + dense 64 -> 128 -> 1 ----
    float* accf = (float*)lds;            // 64*33 = 2112 floats
    float* red = accf + 64 * 33;          // 512 floats (total 2624 <= 3328)
    {
        const int q = tid >> 5, tt = tid & 31;
        float a0 = 0.f, a1 = 0.f, a2 = 0.f, a3 = 0.f;
#pragma unroll
        for (int l = 0; l < 8; ++l) {
            const unsigned* p = pout + (size_t)(l * 256 + bt) * 1024;
            half2_t u0 = h2(p[(2 * q) * 32 + tt]);
            half2_t u1 = h2(p[(2 * q + 1) * 32 + tt]);
            a0 += (float)u0[0]; a1 += (float)u0[1];
            a2 += (float)u1[0]; a3 += (float)u1[1];
        }
        accf[(4 * q + 0) * 33 + tt] = a0;
        accf[(4 * q + 1) * 33 + tt] = a1;
        accf[(4 * q + 2) * 33 + tt] = a2;
        accf[(4 * q + 3) * 33 + tt] = a3;
    }
    __syncthreads();
    {
        const int pg = tid >> 5, tt = tid & 31;  // 16 groups x 8 p
        float partial = 0.f;
#pragma unroll
        for (int pp = 0; pp < 8; ++pp) {
            const int p = pg * 8 + pp;
            float z = d1_b[p];
            const float4* w4 = (const float4*)(d1_w + p * 64);
#pragma unroll 4
            for (int c4 = 0; c4 < 16; ++c4) {
                float4 w = w4[c4];
                z = fmaf(w.x, accf[(c4 * 4 + 0) * 33 + tt], z);
                z = fmaf(w.y, accf[(c4 * 4 + 1) * 33 + tt], z);
                z = fmaf(w.z, accf[(c4 * 4 + 2) * 33 + tt], z);
                z = fmaf(w.w, accf[(c4 * 4 + 3) * 33 + tt], z);
            }
            partial = fmaf(d2_w[p], fmaxf(z, 0.f), partial);
        }
        red[pg * 32 + tt] = partial;
    }
    __syncthreads();
    if (tid < 32) {
        float sum = d2_b[0];
#pragma unroll
        for (int g = 0; g < 16; ++g) sum += red[g * 32 + tid];
        out[bt * 32 + tid] = fmaxf(sum, 0.f);
    }
}

// ================= fallback: fp32 fused (no ws) =================
#define HROW 164
#define SROW 33
__global__ __launch_bounds__(512) void wavenet_main(
    const float* __restrict__ x,
    const float* __restrict__ pre_w, const float* __restrict__ pre_b,
    const float* __restrict__ filt_w, const float* __restrict__ filt_b,
    const float* __restrict__ gate_w, const float* __restrict__ gate_b,
    const float* __restrict__ post_w, const float* __restrict__ post_b,
    const float* __restrict__ d1_w, const float* __restrict__ d1_b,
    const float* __restrict__ d2_w, const float* __restrict__ d2_b,
    float* __restrict__ out)
{
    __shared__ __align__(16) float h_s[64 * HROW];
    __shared__ __align__(16) float wbuf[20480];
    __shared__ __align__(16) float s_s[64 * SROW];
    const int tid = threadIdx.x;
    const int b = blockIdx.x >> 3;
    const int tile = blockIdx.x & 7;
    const int t0 = TFULL - DEC + tile * 32;
    const int lane = tid & 63;
    const int wv = __builtin_amdgcn_readfirstlane(tid >> 6);
    const int q = tid >> 5;
    const int tt = tid & 31;
    float accp[4] = {0.f, 0.f, 0.f, 0.f};
    for (int i = 0; i < 8; ++i) {
        const int dil = 1 << i;
        const int NC = 32 + dil;
        for (int m = tid; m < 8192; m += 512) {
            int c = m >> 7, rem = m & 127, o = rem >> 1, k = m & 1;
            wbuf[m] = filt_w[((i * 64 + o) * 64 + c) * 2 + k];
            wbuf[8192 + m] = gate_w[((i * 64 + o) * 64 + c) * 2 + k];
        }
        for (int m = tid; m < 4096; m += 512) {
            int c = m >> 6, o = m & 63;
            wbuf[16384 + m] = post_w[(i * 64 + o) * 64 + c];
        }
        __syncthreads();
        {
            const float* preb = pre_b + i * 64 + wv * 8;
            const float* prew = pre_w + (i * 64 + wv * 8) * 32;
            for (int col = lane; col < NC; col += 64) {
                int ta = t0 - dil + col;
                const float* xp = x + (size_t)b * 32 * TFULL + ta;
                float hacc[8];
#pragma unroll
                for (int r = 0; r < 8; ++r) hacc[r] = preb[r];
                for (int ci = 0; ci < 32; ++ci) {
                    float xv = xp[ci * TFULL];
#pragma unroll
                    for (int r = 0; r < 8; ++r)
                        hacc[r] = fmaf(prew[r * 32 + ci], xv, hacc[r]);
                }
#pragma unroll
                for (int r = 0; r < 8; ++r)
                    h_s[(wv * 8 + r) * HROW + col] = fmaxf(hacc[r], 0.f);
            }
        }
        __syncthreads();
        {
            float fa[4], ga[4];
#pragma unroll
            for (int oo = 0; oo < 4; ++oo) {
                fa[oo] = filt_b[i * 64 + q * 4 + oo];
                ga[oo] = gate_b[i * 64 + q * 4 + oo];
            }
            const float4* fw4 = (const float4*)wbuf;
            const float4* gw4 = (const float4*)(wbuf + 8192);
            const float* hrow0 = h_s + tt;
            const float* hrow1 = h_s + tt + dil;
#pragma unroll 4
            for (int c = 0; c < 64; ++c) {
                float4 f0 = fw4[c * 32 + q * 2];
                float4 f1 = fw4[c * 32 + q * 2 + 1];
                float4 g0 = gw4[c * 32 + q * 2];
                float4 g1 = gw4[c * 32 + q * 2 + 1];
                float h0 = hrow0[c * HROW];
                float h1 = hrow1[c * HROW];
                fa[0] = fmaf(f0.x, h0, fmaf(f0.y, h1, fa[0]));
                fa[1] = fmaf(f0.z, h0, fmaf(f0.w, h1, fa[1]));
                fa[2] = fmaf(f1.x, h0, fmaf(f1.y, h1, fa[2]));
                fa[3] = fmaf(f1.z, h0, fmaf(f1.w, h1, fa[3]));
                ga[0] = fmaf(g0.x, h0, fmaf(g0.y, h1, ga[0]));
                ga[1] = fmaf(g0.z, h0, fmaf(g0.w, h1, ga[1]));
                ga[2] = fmaf(g1.x, h0, fmaf(g1.y, h1, ga[2]));
                ga[3] = fmaf(g1.z, h0, fmaf(g1.w, h1, ga[3]));
            }
#pragma unroll
            for (int oo = 0; oo < 4; ++oo)
                s_s[(q * 4 + oo) * SROW + tt] = fast_tanh(fa[oo]) * fmaxf(ga[oo], 0.f);
        }
        __syncthreads();
        {
            float pa[4];
#pragma unroll
            for (int oo = 0; oo < 4; ++oo) pa[oo] = post_b[i * 64 + q * 4 + oo];
            const float4* pw4 = (const float4*)(wbuf + 16384);
#pragma unroll 4
            for (int c = 0; c < 64; ++c) {
                float4 pv = pw4[c * 16 + q];
                float sv = s_s[c * SROW + tt];
                pa[0] = fmaf(pv.x, sv, pa[0]);
                pa[1] = fmaf(pv.y, sv, pa[1]);
                pa[2] = fmaf(pv.z, sv, pa[2]);
                pa[3] = fmaf(pv.w, sv, pa[3]);
            }
#pragma unroll
            for (int oo = 0; oo < 4; ++oo) accp[oo] += fmaxf(pa[oo], 0.f);
        }
        __syncthreads();
    }
#pragma unroll
    for (int oo = 0; oo < 4; ++oo) s_s[(q * 4 + oo) * SROW + tt] = accp[oo];
    __syncthreads();
    {
        const int pg = tid >> 5;
        float partial = 0.f;
#pragma unroll
        for (int pp = 0; pp < 8; ++pp) {
            const int p = pg * 8 + pp;
            float z = d1_b[p];
            const float4* w4 = (const float4*)(d1_w + p * 64);
#pragma unroll 4
            for (int c4 = 0; c4 < 16; ++c4) {
                float4 w = w4[c4];
                z = fmaf(w.x, s_s[(c4 * 4 + 0) * SROW + tt], z);
                z = fmaf(w.y, s_s[(c4 * 4 + 1) * SROW + tt], z);
                z = fmaf(w.z, s_s[(c4 * 4 + 2) * SROW + tt], z);
                z = fmaf(w.w, s_s[(c4 * 4 + 3) * SROW + tt], z);
            }
            partial = fmaf(d2_w[p], fmaxf(z, 0.f), partial);
        }
        h_s[pg * 32 + tt] = partial;
    }
    __syncthreads();
    if (tid < 32) {
        float sum = d2_b[0];
#pragma unroll
        for (int g = 0; g < 16; ++g) sum += h_s[g * 32 + tid];
        out[b * DEC + tile * 32 + tid] = fmaxf(sum, 0.f);
    }
}

extern "C" void kernel_launch(void* const* d_in, const int* in_sizes, int n_in,
                              void* d_out, int out_size, void* d_ws, size_t ws_size,
                              hipStream_t stream)
{
    const float* x      = (const float*)d_in[0];
    const float* pre_w  = (const float*)d_in[1];
    const float* pre_b  = (const float*)d_in[2];
    const float* filt_w = (const float*)d_in[3];
    const float* filt_b = (const float*)d_in[4];
    const float* gate_w = (const float*)d_in[5];
    const float* gate_b = (const float*)d_in[6];
    const float* post_w = (const float*)d_in[7];
    const float* post_b = (const float*)d_in[8];
    const float* d1_w   = (const float*)d_in[9];
    const float* d1_b   = (const float*)d_in[10];
    const float* d2_w   = (const float*)d_in[11];
    const float* d2_b   = (const float*)d_in[12];
    float* out = (float*)d_out;

    if (ws_size >= WS_NEEDF) {
        unsigned* ws = (unsigned*)d_ws;
        unsigned* part = ws + XP_U32;
        unsigned* ctr  = ws + CTR_OFF;
        wavenet_prep16<<<689, 512, 0, stream>>>(x, pre_w, filt_w, gate_w, post_w, ws);
        wavenet_mfma2h<<<2048, 512, 0, stream>>>(
            ws, pre_b, filt_b, gate_b, post_b, part, ctr,
            d1_w, d1_b, d2_w, d2_b, out);
    } else {
        wavenet_main<<<256, 512, 0, stream>>>(
            x, pre_w, pre_b, filt_w, filt_b, gate_w, gate_b, post_w, post_b,
            d1_w, d1_b, d2_w, d2_b, out);
    }
}

// Round 9
// 30.650 us; speedup vs baseline: 12.0546x; 12.0546x over previous
//
#include <hip/hip_runtime.h>

typedef _Float16 half2_t __attribute__((ext_vector_type(2)));
typedef _Float16 f16x8 __attribute__((ext_vector_type(8)));
typedef float f32x4 __attribute__((ext_vector_type(4)));

#define DEC 256
#define TFULL 4096
#define WIN0 3584               // x window start (t0min-128 = 3712 >= 3584)
#define WLAYER_U32 11264        // preA 1024 + f 4096 + g 4096 + p 2048
#define WTOT_U32 (8 * WLAYER_U32)          // 90112
#define X16_U32 (32 * 512 * 16)            // 262144, x16t[b][tw512][cp16]
#define P_U32 (8 * 256 * 1024)             // skip partials, f16x2 packed
#define XP_U32 (WTOT_U32 + X16_U32)        // 352256
#define WS_NEED2 ((size_t)(XP_U32 + P_U32) * 4)

#define HSTR 36                 // h LDS row stride (u32), mult of 4 for b128
#define SSTR 36                 // s LDS row stride (u32)
#define HU (64 * HSTR)          // 2304 u32
#define LDS_U32 (HU + 32 * SSTR)  // 3456 u32 = 13824 B

__device__ __forceinline__ float fast_tanh(float x) {
    float xa = fminf(fmaxf(x, -10.f), 10.f);
    float e = __expf(2.f * xa);
    return (e - 1.f) * __builtin_amdgcn_rcpf(e + 1.f);
}
__device__ __forceinline__ unsigned pk_rte(float a, float b) {
    union { _Float16 h[2]; unsigned u; } v;
    v.h[0] = (_Float16)a; v.h[1] = (_Float16)b; return v.u;
}
__device__ __forceinline__ half2_t h2(unsigned u) {
    return __builtin_bit_cast(half2_t, u);
}
__device__ __forceinline__ unsigned pkrtz(float a, float b) {
    return __builtin_bit_cast(unsigned, __builtin_amdgcn_cvt_pkrtz(a, b));
}

// ---------------- prep: pack weights + x window to f16 ----------------
// per-layer block (u32), all in the MFMA A-frag convention (A and B share
// the same k-permutation; only consistency matters):
//   [0,1024)     preA[kg4][o64][e4]   k=cin: u32 = (pre[o][8kg+2e], [+1])
//   [1024,5120)  f16 [kb16][o64][e4]  kb=4m+h4, m=MFMA idx: tap=m>>1,
//                c = 32*(m&1)+8*h4+2e: u32 = (fw[o][c][tap], fw[o][c+1][tap])
//   [5120,9216)  g16 same
//   [9216,11264) p16 [kg8][o64][e4]   k=c: u32 = (pw[o][8kg+2e], [+1])
// then x16t[b32][tw512][cp16] at WTOT_U32 (transposed for B-frag uint4 loads).
__global__ __launch_bounds__(512) void wavenet_prep16(
    const float* __restrict__ x,
    const float* __restrict__ pre_w,
    const float* __restrict__ fw, const float* __restrict__ gw,
    const float* __restrict__ pw, unsigned* __restrict__ ws)
{
    int idx = blockIdx.x * 512 + threadIdx.x;
    if (idx >= XP_U32) return;
    unsigned v;
    if (idx < WTOT_U32) {
        int i = idx / WLAYER_U32;
        int r = idx - i * WLAYER_U32;
        if (r < 1024) {
            int kg = r >> 8, o = (r >> 2) & 63, e = r & 3;
            const float* p = pre_w + (i * 64 + o) * 32 + 8 * kg + 2 * e;
            v = pk_rte(p[0], p[1]);
        } else if (r < 9216) {
            const int isg = (r >= 5120);
            int e2 = r - (isg ? 5120 : 1024);
            int kb = e2 >> 8, o = (e2 >> 2) & 63, e = e2 & 3;
            int m = kb >> 2, h4g = kb & 3;
            int tap = m >> 1;
            int c = 32 * (m & 1) + 8 * h4g + 2 * e;
            const float* src = isg ? gw : fw;
            const float* p = src + ((i * 64 + o) * 64 + c) * 2 + tap;
            v = pk_rte(p[0], p[2]);   // (w[o][c][tap], w[o][c+1][tap])
        } else {
            int e3 = r - 9216;
            int kg = e3 >> 8, o = (e3 >> 2) & 63, e = e3 & 3;
            const float* p = pw + (i * 64 + o) * 64 + 8 * kg + 2 * e;
            v = pk_rte(p[0], p[1]);
        }
    } else {
        int e = idx - WTOT_U32;
        int b = e >> 13, r2 = e & 8191;
        int tw = r2 >> 4, cp = r2 & 15;
        const float* p = x + (size_t)(b * 32 + 2 * cp) * TFULL + WIN0 + tw;
        v = pk_rte(p[0], p[TFULL]);
    }
    ws[idx] = v;
}

// ---------------- layer-parallel all-MFMA kernel ----------------
// grid 2048 = layer(8) x bt(256); 512 threads; LDS 13824 B.
// Wave w: o-tile mt = w>>1; col-half nt = w&1.
__global__ __launch_bounds__(512) void wavenet_mfma2(
    const unsigned* __restrict__ wsu,
    const float* __restrict__ pre_b,
    const float* __restrict__ filt_b, const float* __restrict__ gate_b,
    const float* __restrict__ post_b,
    unsigned* __restrict__ pout)
{
    __shared__ __align__(16) unsigned lds[LDS_U32];

    const int tid = threadIdx.x;
    const int i = blockIdx.x >> 8;
    const int bt = blockIdx.x & 255;
    const int b = bt >> 3;
    const int tile = bt & 7;
    const int dil = 1 << i;
    const int off1 = (dil < 32) ? dil : 32;
    const int t0 = TFULL - DEC + tile * 32;

    const int lane = tid & 63;
    const int wv = __builtin_amdgcn_readfirstlane(tid >> 6); // 0..7
    const int h4 = lane >> 4;       // 0..3 (k-group)
    const int ln = lane & 15;       // row/col within tile
    const int mt = wv >> 1;         // o-tile
    const int nt = wv & 1;          // col-half for P2/P3

    const unsigned* xw = wsu + WTOT_U32 + b * 8192;
    const unsigned* wl = wsu + i * WLAYER_U32;

    // ---- P1 (MFMA): h[o64][cw64] = relu(pre . x); store [cw][o] f16 ----
    {
        f16x8 a = *(const f16x8*)(wl + (h4 * 64 + mt * 16 + ln) * 4);
        float4 pb4 = *(const float4*)(pre_b + i * 64 + mt * 16 + 4 * h4);
#pragma unroll
        for (int ct2 = 0; ct2 < 2; ++ct2) {
            const int cw = (2 * nt + ct2) * 16 + ln;  // window col
            int ta = (dil >= 32) ? ((cw < 32) ? (t0 - dil + cw) : (t0 + cw - 32))
                                 : (t0 - dil + cw);
            const int tw = (ta - WIN0) & 511;   // wrap unused tail cols
            f16x8 bx = *(const f16x8*)(xw + tw * 16 + h4 * 4);
            f32x4 c = {0.f, 0.f, 0.f, 0.f};
            c = __builtin_amdgcn_mfma_f32_16x16x32_f16(a, bx, c, 0, 0, 0);
            // rows o = mt*16 + 4*h4 + reg, col cw; u32 j = (h[cw][2j], h[cw][2j+1])
            uint2 hv;
            hv.x = pkrtz(fmaxf(c[0] + pb4.x, 0.f), fmaxf(c[1] + pb4.y, 0.f));
            hv.y = pkrtz(fmaxf(c[2] + pb4.z, 0.f), fmaxf(c[3] + pb4.w, 0.f));
            *(uint2*)&lds[cw * HSTR + mt * 8 + h4 * 2] = hv;
        }
    }
    __syncthreads();

    const int t = nt * 16 + ln;     // output col 0..31

    // ---- P2 (MFMA): F,G. k-order = [tap0 c0..63 | tap1 c0..63]:
    //      MFMA m reads B directly from h row (t or t+off1), no repack ----
    {
        f32x4 cf = {0.f, 0.f, 0.f, 0.f};
        f32x4 cg = {0.f, 0.f, 0.f, 0.f};
        const unsigned* fA = wl + 1024;
        const unsigned* gA = wl + 5120;
#pragma unroll
        for (int m = 0; m < 4; ++m) {
            const int kbg = 4 * m + h4;
            const int row = (m >> 1) ? (t + off1) : t;       // tap select
            uint4 bf = *(const uint4*)&lds[row * HSTR + 16 * (m & 1) + 4 * h4];
            f16x8 bfrag = __builtin_bit_cast(f16x8, bf);
            f16x8 af = *(const f16x8*)(fA + (kbg * 64 + mt * 16 + ln) * 4);
            f16x8 ag = *(const f16x8*)(gA + (kbg * 64 + mt * 16 + ln) * 4);
            cf = __builtin_amdgcn_mfma_f32_16x16x32_f16(af, bfrag, cf, 0, 0, 0);
            cg = __builtin_amdgcn_mfma_f32_16x16x32_f16(ag, bfrag, cg, 0, 0, 0);
        }
        float4 fb = *(const float4*)(filt_b + i * 64 + mt * 16 + 4 * h4);
        float4 gb = *(const float4*)(gate_b + i * 64 + mt * 16 + 4 * h4);
        float s0 = fast_tanh(cf[0] + fb.x) * fmaxf(cg[0] + gb.x, 0.f);
        float s1 = fast_tanh(cf[1] + fb.y) * fmaxf(cg[1] + gb.y, 0.f);
        float s2 = fast_tanh(cf[2] + fb.z) * fmaxf(cg[2] + gb.z, 0.f);
        float s3 = fast_tanh(cf[3] + fb.w) * fmaxf(cg[3] + gb.w, 0.f);
        uint2 sv;
        sv.x = pkrtz(s0, s1);
        sv.y = pkrtz(s2, s3);
        *(uint2*)&lds[HU + t * SSTR + mt * 8 + h4 * 2] = sv;
    }
    __syncthreads();

    // ---- P3 (MFMA): P (K=64, k=c); coalesced uint2 partial write ----
    {
        f32x4 cp = {0.f, 0.f, 0.f, 0.f};
        const unsigned* pA = wl + 9216;
#pragma unroll
        for (int ki = 0; ki < 2; ++ki) {
            const int kg = 4 * ki + h4;      // c0 = 8*kg
            f16x8 bs = *(const f16x8*)&lds[HU + t * SSTR + 4 * kg];
            f16x8 ap = *(const f16x8*)(pA + (kg * 64 + mt * 16 + ln) * 4);
            cp = __builtin_amdgcn_mfma_f32_16x16x32_f16(ap, bs, cp, 0, 0, 0);
        }
        float4 pb = *(const float4*)(post_b + i * 64 + mt * 16 + 4 * h4);
        // partial layout: [q16][t32][2] u32, q = o>>2 = mt*4+h4
        uint2 o2;
        o2.x = pkrtz(fmaxf(cp[0] + pb.x, 0.f), fmaxf(cp[1] + pb.y, 0.f));
        o2.y = pkrtz(fmaxf(cp[2] + pb.z, 0.f), fmaxf(cp[3] + pb.w, 0.f));
        unsigned* po = pout + (size_t)(i * 256 + bt) * 1024;
        *(uint2*)&po[(mt * 4 + h4) * 64 + 2 * t] = o2;
    }
}

// ---------------- head: skip-sum + dense 64 -> 128 -> 1 ----------------
__global__ __launch_bounds__(512) void wavenet_head16(
    const unsigned* __restrict__ pin,
    const float* __restrict__ d1_w, const float* __restrict__ d1_b,
    const float* __restrict__ d2_w, const float* __restrict__ d2_b,
    float* __restrict__ out)
{
    __shared__ __align__(16) float accf[64 * 33];
    __shared__ float red[512];
    const int tid = threadIdx.x;
    const int bt = blockIdx.x;          // b*8 + tile
    const int q = tid >> 5, tt = tid & 31;

    float a[4] = {0.f, 0.f, 0.f, 0.f};
#pragma unroll
    for (int l = 0; l < 8; ++l) {
        const unsigned* p = pin + (size_t)(l * 256 + bt) * 1024;
        uint2 u = *(const uint2*)&p[q * 64 + 2 * tt];
        half2_t u0 = h2(u.x), u1 = h2(u.y);
        a[0] += (float)u0[0]; a[1] += (float)u0[1];
        a[2] += (float)u1[0]; a[3] += (float)u1[1];
    }
#pragma unroll
    for (int oo = 0; oo < 4; ++oo) accf[(4 * q + oo) * 33 + tt] = a[oo];
    __syncthreads();

    {
        const int pg = tid >> 5;  // 16 groups x 8 p
        float partial = 0.f;
#pragma unroll
        for (int pp = 0; pp < 8; ++pp) {
            const int p = pg * 8 + pp;
            float z = d1_b[p];
            const float4* w4 = (const float4*)(d1_w + p * 64);
#pragma unroll 4
            for (int c4 = 0; c4 < 16; ++c4) {
                float4 w = w4[c4];
                z = fmaf(w.x, accf[(c4 * 4 + 0) * 33 + tt], z);
                z = fmaf(w.y, accf[(c4 * 4 + 1) * 33 + tt], z);
                z = fmaf(w.z, accf[(c4 * 4 + 2) * 33 + tt], z);
                z = fmaf(w.w, accf[(c4 * 4 + 3) * 33 + tt], z);
            }
            partial = fmaf(d2_w[p], fmaxf(z, 0.f), partial);
        }
        red[pg * 32 + tt] = partial;
    }
    __syncthreads();
    if (tid < 32) {
        float sum = d2_b[0];
#pragma unroll
        for (int g = 0; g < 16; ++g) sum += red[g * 32 + tid];
        out[bt * 32 + tid] = fmaxf(sum, 0.f);
    }
}

// ================= fallback: fp32 fused (no ws) =================
#define HROW 164
#define SROW 33
__global__ __launch_bounds__(512) void wavenet_main(
    const float* __restrict__ x,
    const float* __restrict__ pre_w, const float* __restrict__ pre_b,
    const float* __restrict__ filt_w, const float* __restrict__ filt_b,
    const float* __restrict__ gate_w, const float* __restrict__ gate_b,
    const float* __restrict__ post_w, const float* __restrict__ post_b,
    const float* __restrict__ d1_w, const float* __restrict__ d1_b,
    const float* __restrict__ d2_w, const float* __restrict__ d2_b,
    float* __restrict__ out)
{
    __shared__ __align__(16) float h_s[64 * HROW];
    __shared__ __align__(16) float wbuf[20480];
    __shared__ __align__(16) float s_s[64 * SROW];
    const int tid = threadIdx.x;
    const int b = blockIdx.x >> 3;
    const int tile = blockIdx.x & 7;
    const int t0 = TFULL - DEC + tile * 32;
    const int lane = tid & 63;
    const int wv = __builtin_amdgcn_readfirstlane(tid >> 6);
    const int q = tid >> 5;
    const int tt = tid & 31;
    float accp[4] = {0.f, 0.f, 0.f, 0.f};
    for (int i = 0; i < 8; ++i) {
        const int dil = 1 << i;
        const int NC = 32 + dil;
        for (int m = tid; m < 8192; m += 512) {
            int c = m >> 7, rem = m & 127, o = rem >> 1, k = m & 1;
            wbuf[m] = filt_w[((i * 64 + o) * 64 + c) * 2 + k];
            wbuf[8192 + m] = gate_w[((i * 64 + o) * 64 + c) * 2 + k];
        }
        for (int m = tid; m < 4096; m += 512) {
            int c = m >> 6, o = m & 63;
            wbuf[16384 + m] = post_w[(i * 64 + o) * 64 + c];
        }
        __syncthreads();
        {
            const float* preb = pre_b + i * 64 + wv * 8;
            const float* prew = pre_w + (i * 64 + wv * 8) * 32;
            for (int col = lane; col < NC; col += 64) {
                int ta = t0 - dil + col;
                const float* xp = x + (size_t)b * 32 * TFULL + ta;
                float hacc[8];
#pragma unroll
                for (int r = 0; r < 8; ++r) hacc[r] = preb[r];
                for (int ci = 0; ci < 32; ++ci) {
                    float xv = xp[ci * TFULL];
#pragma unroll
                    for (int r = 0; r < 8; ++r)
                        hacc[r] = fmaf(prew[r * 32 + ci], xv, hacc[r]);
                }
#pragma unroll
                for (int r = 0; r < 8; ++r)
                    h_s[(wv * 8 + r) * HROW + col] = fmaxf(hacc[r], 0.f);
            }
        }
        __syncthreads();
        {
            float fa[4], ga[4];
#pragma unroll
            for (int oo = 0; oo < 4; ++oo) {
                fa[oo] = filt_b[i * 64 + q * 4 + oo];
                ga[oo] = gate_b[i * 64 + q * 4 + oo];
            }
            const float4* fw4 = (const float4*)wbuf;
            const float4* gw4 = (const float4*)(wbuf + 8192);
            const float* hrow0 = h_s + tt;
            const float* hrow1 = h_s + tt + dil;
#pragma unroll 4
            for (int c = 0; c < 64; ++c) {
                float4 f0 = fw4[c * 32 + q * 2];
                float4 f1 = fw4[c * 32 + q * 2 + 1];
                float4 g0 = gw4[c * 32 + q * 2];
                float4 g1 = gw4[c * 32 + q * 2 + 1];
                float h0 = hrow0[c * HROW];
                float h1 = hrow1[c * HROW];
                fa[0] = fmaf(f0.x, h0, fmaf(f0.y, h1, fa[0]));
                fa[1] = fmaf(f0.z, h0, fmaf(f0.w, h1, fa[1]));
                fa[2] = fmaf(f1.x, h0, fmaf(f1.y, h1, fa[2]));
                fa[3] = fmaf(f1.z, h0, fmaf(f1.w, h1, fa[3]));
                ga[0] = fmaf(g0.x, h0, fmaf(g0.y, h1, ga[0]));
                ga[1] = fmaf(g0.z, h0, fmaf(g0.w, h1, ga[1]));
                ga[2] = fmaf(g1.x, h0, fmaf(g1.y, h1, ga[2]));
                ga[3] = fmaf(g1.z, h0, fmaf(g1.w, h1, ga[3]));
            }
#pragma unroll
            for (int oo = 0; oo < 4; ++oo)
                s_s[(q * 4 + oo) * SROW + tt] = fast_tanh(fa[oo]) * fmaxf(ga[oo], 0.f);
        }
        __syncthreads();
        {
            float pa[4];
#pragma unroll
            for (int oo = 0; oo < 4; ++oo) pa[oo] = post_b[i * 64 + q * 4 + oo];
            const float4* pw4 = (const float4*)(wbuf + 16384);
#pragma unroll 4
            for (int c = 0; c < 64; ++c) {
                float4 pv = pw4[c * 16 + q];
                float sv = s_s[c * SROW + tt];
                pa[0] = fmaf(pv.x, sv, pa[0]);
                pa[1] = fmaf(pv.y, sv, pa[1]);
                pa[2] = fmaf(pv.z, sv, pa[2]);
                pa[3] = fmaf(pv.w, sv, pa[3]);
            }
#pragma unroll
            for (int oo = 0; oo < 4; ++oo) accp[oo] += fmaxf(pa[oo], 0.f);
        }
        __syncthreads();
    }
#pragma unroll
    for (int oo = 0; oo < 4; ++oo) s_s[(q * 4 + oo) * SROW + tt] = accp[oo];
    __syncthreads();
    {
        const int pg = tid >> 5;
        float partial = 0.f;
#pragma unroll
        for (int pp = 0; pp < 8; ++pp) {
            const int p = pg * 8 + pp;
            float z = d1_b[p];
            const float4* w4 = (const float4*)(d1_w + p * 64);
#pragma unroll 4
            for (int c4 = 0; c4 < 16; ++c4) {
                float4 w = w4[c4];
                z = fmaf(w.x, s_s[(c4 * 4 + 0) * SROW + tt], z);
                z = fmaf(w.y, s_s[(c4 * 4 + 1) * SROW + tt], z);
                z = fmaf(w.z, s_s[(c4 * 4 + 2) * SROW + tt], z);
                z = fmaf(w.w, s_s[(c4 * 4 + 3) * SROW + tt], z);
            }
            partial = fmaf(d2_w[p], fmaxf(z, 0.f), partial);
        }
        h_s[pg * 32 + tt] = partial;
    }
    __syncthreads();
    if (tid < 32) {
        float sum = d2_b[0];
#pragma unroll
        for (int g = 0; g < 16; ++g) sum += h_s[g * 32 + tid];
        out[b * DEC + tile * 32 + tid] = fmaxf(sum, 0.f);
    }
}

extern "C" void kernel_launch(void* const* d_in, const int* in_sizes, int n_in,
                              void* d_out, int out_size, void* d_ws, size_t ws_size,
                              hipStream_t stream)
{
    const float* x      = (const float*)d_in[0];
    const float* pre_w  = (const float*)d_in[1];
    const float* pre_b  = (const float*)d_in[2];
    const float* filt_w = (const float*)d_in[3];
    const float* filt_b = (const float*)d_in[4];
    const float* gate_w = (const float*)d_in[5];
    const float* gate_b = (const float*)d_in[6];
    const float* post_w = (const float*)d_in[7];
    const float* post_b = (const float*)d_in[8];
    const float* d1_w   = (const float*)d_in[9];
    const float* d1_b   = (const float*)d_in[10];
    const float* d2_w   = (const float*)d_in[11];
    const float* d2_b   = (const float*)d_in[12];
    float* out = (float*)d_out;

    if (ws_size >= WS_NEED2) {
        unsigned* ws = (unsigned*)d_ws;
        unsigned* part = ws + XP_U32;
        wavenet_prep16<<<688, 512, 0, stream>>>(x, pre_w, filt_w, gate_w, post_w, ws);
        wavenet_mfma2<<<2048, 512, 0, stream>>>(
            ws, pre_b, filt_b, gate_b, post_b, part);
        wavenet_head16<<<256, 512, 0, stream>>>(
            part, d1_w, d1_b, d2_w, d2_b, out);
    } else {
        wavenet_main<<<256, 512, 0, stream>>>(
            x, pre_w, pre_b, filt_w, filt_b, gate_w, gate_b, post_w, post_b,
            d1_w, d1_b, d2_w, d2_b, out);
    }
}